// Round 1
// baseline (86.718 us; speedup 1.0000x reference)
//
#include <hip/hip_runtime.h>
#include <hip/hip_bf16.h>

#define N 8192
#define D 128
#define LOG2E  1.44269504088896f
#define LN2    0.69314718055995f

typedef __attribute__((ext_vector_type(8))) short bf16x8;
typedef __attribute__((ext_vector_type(4))) float f32x4;

#if __has_builtin(__builtin_amdgcn_exp2f)
#define EXP2(x) __builtin_amdgcn_exp2f(x)
#else
#define EXP2(x) exp2f(x)
#endif
#if __has_builtin(__builtin_amdgcn_logf)
#define LOG2(x) __builtin_amdgcn_logf(x)
#else
#define LOG2(x) log2f(x)
#endif

typedef const __attribute__((address_space(1))) unsigned int as1_u32c;
typedef __attribute__((address_space(3))) unsigned int as3_u32;

static __device__ __forceinline__ unsigned short f2bf(float f) {
    union { float f; unsigned int u; } x;
    x.f = f;
    unsigned int r = ((x.u >> 16) & 1u) + 0x7FFFu;  // round-to-nearest-even
    return (unsigned short)((x.u + r) >> 16);
}

// Kernel 1 (R11): E (fp32) -> Eb2 (bf16) in FRAGMENT-MAJOR layout.
// Chunk (S,kk,lane) at byte S*4096 + kk*1024 + lane*16 so every MFMA
// fragment load is one contiguous 1-KB wave-load. R12: also zeroes
// rowsum[8192] (part/bpart/counter are gone — credits go straight to
// rowsum via atomicAdd in fused).
__global__ void prep_kernel(const float* __restrict__ E,
                            uint4* __restrict__ Eb2,
                            float* __restrict__ rowsum) {
    const int j = blockIdx.x * 256 + threadIdx.x;   // 0..131071
    const int l  = j & 15;
    const int q  = (j >> 4) & 3;
    const int kk = (j >> 6) & 3;
    const int S  = j >> 8;
    const float4* src = (const float4*)(E + (size_t)(S * 16 + l) * D + kk * 32 + q * 8);
    float4 f0 = src[0], f1 = src[1];
    uint4 o;
    o.x = f2bf(f0.x) | ((unsigned)f2bf(f0.y) << 16);
    o.y = f2bf(f0.z) | ((unsigned)f2bf(f0.w) << 16);
    o.z = f2bf(f1.x) | ((unsigned)f2bf(f1.y) << 16);
    o.w = f2bf(f1.z) | ((unsigned)f2bf(f1.w) << 16);
    Eb2[j] = o;
    if (j < N) rowsum[j] = 0.0f;
}

// Kernel 2 (R12): A frags direct from fragment-major Eb2 (unchanged, no
// redundancy — each wave owns its rows). B tile (32 KB) staged ONCE per
// block into LDS via global_load_lds: previously all 4 waves loaded the
// identical B data from global (128 KB/block for 32 KB unique). Staging
// map: wave wid stages chunks m = wid*8+u (1 KB each, dest wave-uniform
// base + lane*16 — satisfies the global_load_lds linear-dest rule).
// Single vmcnt(0)+barrier up front; s-loop is barrier-free ds_read_b128
// (contiguous 1 KB per chunk -> conflict-free). LDS = 32 KB + 1.5 KB ->
// 4 blocks/CU, matching the VGPR-bound occupancy. Row/col credits now
// atomicAdd straight into rowsum (R9 exonerated global atomics).
__global__ __launch_bounds__(256) void fused_kernel(
        const unsigned short* __restrict__ Eb2,
        const int* __restrict__ labels,
        float* __restrict__ rowsum) {
    __shared__ uint4 btile4[2048];          // 32 KB B tile
    __shared__ int   labC[128];
    __shared__ int   labR[128];
    __shared__ float colacc[128];

    const int tid  = threadIdx.x;
    const int wid  = tid >> 6;     // 0..3
    const int lane = tid & 63;
    const int q = lane >> 4;       // 0..3
    const int l = lane & 15;       // 0..15

    // Triangular tile decode b -> (r, c), r <= c, 64 row-tiles (128 wide).
    const int b = blockIdx.x;
    int r = (int)(64.5f - sqrtf(64.5f * 64.5f - 2.0f * (float)b));
    while ((r + 1) * 64 - ((r + 1) * r) / 2 <= b) ++r;
    while (r * 64 - (r * (r - 1)) / 2 > b) --r;
    const int c = r + (b - (r * 64 - (r * (r - 1)) / 2));
    const bool diag = (r == c);
    const int tile_m0 = r * 128;
    const int n_begin = c * 128;
    const int mrow0 = wid * 32;            // wave's row strip within tile

    const char* base = (const char*)Eb2;
    char* bt = (char*)btile4;

    // A fragments: row-group S_A = r*8 + wid*2 + g. Contiguous 1-KB wave-loads.
    bf16x8 a[2][4];
#pragma unroll
    for (int g = 0; g < 2; ++g) {
        const char* pa = base + (size_t)(r * 8 + wid * 2 + g) * 4096 + lane * 16;
#pragma unroll
        for (int kk = 0; kk < 4; ++kk)
            a[g][kk] = *(const bf16x8*)(pa + kk * 1024);
    }

    // B tile -> LDS, once. 32 chunks of 1 KB; wave wid stages 8 of them.
    {
        const char* gB = base + (size_t)(c * 8) * 4096;
#pragma unroll
        for (int u = 0; u < 8; ++u) {
            const int m = wid * 8 + u;
            __builtin_amdgcn_global_load_lds(
                (as1_u32c*)(gB + m * 1024 + lane * 16),
                (as3_u32*)(bt + m * 1024),
                16, 0, 0);
        }
    }

    if (tid < 128) { labC[tid] = labels[n_begin + tid]; colacc[tid] = 0.0f; }
    else           { labR[tid - 128] = labels[tile_m0 + (tid - 128)]; }
    asm volatile("s_waitcnt vmcnt(0)" ::: "memory");  // drain global_load_lds
    __syncthreads();

    int lrow[8];
#pragma unroll
    for (int g = 0; g < 2; ++g)
#pragma unroll
        for (int rr = 0; rr < 4; ++rr)
            lrow[g * 4 + rr] = labR[mrow0 + g * 16 + q * 4 + rr];

    float sum[8];
#pragma unroll
    for (int i = 0; i < 8; ++i) sum[i] = 0.0f;

    // ---- compute: 8 subtiles of 16 cols; B frags from LDS, barrier-free ----
#pragma clang loop unroll(disable)
    for (int s = 0; s < 8; ++s) {
        const char* pb = bt + s * 4096 + lane * 16;
        bf16x8 b0 = *(const bf16x8*)(pb);
        bf16x8 b1 = *(const bf16x8*)(pb + 1024);
        bf16x8 b2 = *(const bf16x8*)(pb + 2048);
        bf16x8 b3 = *(const bf16x8*)(pb + 3072);
        const int lc = labC[s * 16 + l];

        f32x4 acc0 = (f32x4){0.f, 0.f, 0.f, 0.f};
        f32x4 acc1 = (f32x4){0.f, 0.f, 0.f, 0.f};
        acc0 = __builtin_amdgcn_mfma_f32_16x16x32_bf16(a[0][0], b0, acc0, 0, 0, 0);
        acc0 = __builtin_amdgcn_mfma_f32_16x16x32_bf16(a[0][1], b1, acc0, 0, 0, 0);
        acc0 = __builtin_amdgcn_mfma_f32_16x16x32_bf16(a[0][2], b2, acc0, 0, 0, 0);
        acc0 = __builtin_amdgcn_mfma_f32_16x16x32_bf16(a[0][3], b3, acc0, 0, 0, 0);
        acc1 = __builtin_amdgcn_mfma_f32_16x16x32_bf16(a[1][0], b0, acc1, 0, 0, 0);
        acc1 = __builtin_amdgcn_mfma_f32_16x16x32_bf16(a[1][1], b1, acc1, 0, 0, 0);
        acc1 = __builtin_amdgcn_mfma_f32_16x16x32_bf16(a[1][2], b2, acc1, 0, 0, 0);
        acc1 = __builtin_amdgcn_mfma_f32_16x16x32_bf16(a[1][3], b3, acc1, 0, 0, 0);

        float cp = 0.0f;
#pragma unroll
        for (int g = 0; g < 2; ++g) {
#pragma unroll
            for (int rr = 0; rr < 4; ++rr) {
                float sv = (g == 0) ? acc0[rr] : acc1[rr];
                bool eq = (lrow[g * 4 + rr] == lc);
                float cc = eq ? -LOG2E : LOG2E;
                float term = EXP2(cc * (sv - 0.1f));
                sum[g * 4 + rr] += term;
                cp += term;
            }
        }
        if (!diag) {
            cp += __shfl_xor(cp, 16);   // reduce over q-quarters
            cp += __shfl_xor(cp, 32);
            if (q == 0) atomicAdd(&colacc[s * 16 + l], cp);  // LDS only
        }
    }

    // Row credits: reduce across the 16 column-lanes, atomicAdd to rowsum.
#pragma unroll
    for (int i = 0; i < 8; ++i) {
        float v = sum[i];
        v += __shfl_xor(v, 1);
        v += __shfl_xor(v, 2);
        v += __shfl_xor(v, 4);
        v += __shfl_xor(v, 8);
        sum[i] = v;
    }
    if (l == 0) {
#pragma unroll
        for (int g = 0; g < 2; ++g)
#pragma unroll
            for (int rr = 0; rr < 4; ++rr)
                atomicAdd(&rowsum[tile_m0 + mrow0 + g * 16 + q * 4 + rr],
                          sum[g * 4 + rr]);
    }

    // Col credits (off-diagonal only): symmetric contribution to rows n_begin..
    __syncthreads();
    if (!diag && tid < 128)
        atomicAdd(&rowsum[n_begin + tid], colacc[tid]);
}

// Kernel 3 (R12): trivial — 1 block, 32 KB read, log + mean.
__global__ void finalize_kernel(const float* __restrict__ rowsum,
                                float* __restrict__ out) {
    __shared__ float red[4];
    const int tid = threadIdx.x;
    float v = 0.0f;
#pragma unroll 8
    for (int k = 0; k < 32; ++k) v += LOG2(rowsum[tid + 256 * k]);
    v *= LN2;
#pragma unroll
    for (int off = 1; off <= 32; off <<= 1) v += __shfl_xor(v, off);
    if ((tid & 63) == 0) red[tid >> 6] = v;
    __syncthreads();
    if (tid == 0)
        out[0] = (red[0] + red[1] + red[2] + red[3]) * (1.0f / (float)N);
}

extern "C" void kernel_launch(void* const* d_in, const int* in_sizes, int n_in,
                              void* d_out, int out_size, void* d_ws, size_t ws_size,
                              hipStream_t stream) {
    const float* E = (const float*)d_in[0];
    const int* labels = (const int*)d_in[1];
    float* out = (float*)d_out;

    unsigned short* Eb2 = (unsigned short*)d_ws;                // 2 MiB, fragment-major
    float* rowsum = (float*)((char*)d_ws + (size_t)N * D * 2);  // 8192 floats

    prep_kernel<<<512, 256, 0, stream>>>(E, (uint4*)Eb2, rowsum);
    fused_kernel<<<2080, 256, 0, stream>>>(Eb2, labels, rowsum);
    finalize_kernel<<<1, 256, 0, stream>>>(rowsum, out);
}